// Round 3
// baseline (288.217 us; speedup 1.0000x reference)
//
#include <hip/hip_runtime.h>

#define N_NODES 50000
#define N_EDGES 800000
#define HID 128
#define CAP 32        // per-node bucket = 32 ints = exactly 1 cache line
#define OVF_CAP 16384

typedef float f4v __attribute__((ext_vector_type(4)));

// ---------------- bucket edges by dst: buckets[dst][pos] = src ----------------
__global__ __launch_bounds__(256) void bucket_k(const int* __restrict__ EI,
                                                int* __restrict__ buckets,
                                                int* __restrict__ cnt,
                                                int* __restrict__ ovf_cnt,
                                                int* __restrict__ ovf) {
  const int e = blockIdx.x * blockDim.x + threadIdx.x;
  if (e >= N_EDGES) return;
  const int dst = EI[e];            // row 0 = destination
  const int src = EI[N_EDGES + e];  // row 1 = source
  const int pos = atomicAdd(cnt + dst, 1);
  if (pos < CAP) {
    buckets[(size_t)dst * CAP + pos] = src;
  } else {
    const int oi = atomicAdd(ovf_cnt, 1);
    if (oi < OVF_CAP) ovf[oi] = e;
  }
}

// ---------------- Y[d] = (X[d] + sum_src X[src]) / (1+deg[d]) ----------------
// Column-chunked, high-MLP gather:
//   block = 256 threads = 4 waves; wave = 16 nodes x 4 lanes; lane = float4.
//   chunk = blockIdx.x & 7 -> 16-col slice (3.2 MB of X, fits one XCD L2 if
//   blocks round-robin XCDs). One X-load instruction = 16 independent 64B
//   segments -> 16x MLP vs one-row-per-wave. Bucket reads + Y writes are
//   nontemporal so the streaming data doesn't evict the resident X slice.
__global__ __launch_bounds__(256) void gatherc_k(const float* __restrict__ X,
                                                 const int* __restrict__ buckets,
                                                 const int* __restrict__ cnt,
                                                 float* __restrict__ Y) {
  const int chunk = blockIdx.x & 7;
  const int nb = blockIdx.x >> 3;
  const int lane = threadIdx.x & 63;
  const int node = nb * 64 + (threadIdx.x >> 6) * 16 + (lane >> 2);
  const int c0 = chunk * 16 + (lane & 3) * 4;
  const bool valid = node < N_NODES;
  const int deg = valid ? cnt[node] : 0;
  const int m = deg < CAP ? deg : CAP;
  const size_t boff = (size_t)node * CAP;
  f4v acc = {0.f, 0.f, 0.f, 0.f};
  for (int j0 = 0; j0 < CAP; j0 += 8) {
    if (!__any(j0 < m)) break;
#pragma unroll
    for (int jj = 0; jj < 8; ++jj) {
      const int j = j0 + jj;
      if (j < m) {
        const int s = __builtin_nontemporal_load(buckets + boff + j);
        const f4v v = *(const f4v*)(X + (size_t)s * HID + c0);
        acc += v;
      }
    }
  }
  if (valid) {
    const f4v self = *(const f4v*)(X + (size_t)node * HID + c0);
    const float inv = 1.0f / (float)(deg + 1);
    f4v o = (acc + self) * inv;
    __builtin_nontemporal_store(o, (f4v*)(Y + (size_t)node * HID + c0));
  }
}

// ---------------- out = Y @ W^T + b, IN PLACE over Y (d_out) ----------------
// 64 rows x ALL 128 cols per block -> in-place safe (no cross-block row reuse).
__global__ __launch_bounds__(256) void gemm_k(const float* __restrict__ Y,
                                              const float* __restrict__ W,
                                              const float* __restrict__ B,
                                              float* __restrict__ OUT) {
  __shared__ __align__(16) float As[32][68];
  __shared__ __align__(16) float Bs[32][132];
  const int t = threadIdx.x;
  const int tx = t & 15;  // cols [tx*8, tx*8+8)
  const int ty = t >> 4;  // rows [ty*4, ty*4+4)
  const int i0 = blockIdx.x * 64;
  float acc[4][8];
#pragma unroll
  for (int r = 0; r < 4; ++r)
#pragma unroll
    for (int c = 0; c < 8; ++c) acc[r][c] = 0.f;

  for (int kc = 0; kc < HID; kc += 32) {
#pragma unroll
    for (int it = 0; it < 2; ++it) {
      const int v = t + it * 256;
      const int row = v >> 3;
      const int c4 = v & 7;
      float4 a = make_float4(0.f, 0.f, 0.f, 0.f);
      if (i0 + row < N_NODES)
        a = *(const float4*)(Y + (size_t)(i0 + row) * HID + kc + c4 * 4);
      As[c4 * 4 + 0][row] = a.x;
      As[c4 * 4 + 1][row] = a.y;
      As[c4 * 4 + 2][row] = a.z;
      As[c4 * 4 + 3][row] = a.w;
    }
#pragma unroll
    for (int it = 0; it < 4; ++it) {
      const int v = t + it * 256;
      const int j = v >> 3;
      const int c4 = v & 7;
      const float4 w = *(const float4*)(W + (size_t)j * HID + kc + c4 * 4);
      Bs[c4 * 4 + 0][j] = w.x;
      Bs[c4 * 4 + 1][j] = w.y;
      Bs[c4 * 4 + 2][j] = w.z;
      Bs[c4 * 4 + 3][j] = w.w;
    }
    __syncthreads();
#pragma unroll
    for (int k = 0; k < 32; ++k) {
      const float4 av = *(const float4*)&As[k][ty * 4];
      const float4 b0 = *(const float4*)&Bs[k][tx * 8];
      const float4 b1 = *(const float4*)&Bs[k][tx * 8 + 4];
      const float a0 = av.x, a1 = av.y, a2 = av.z, a3 = av.w;
      acc[0][0] = fmaf(a0, b0.x, acc[0][0]);
      acc[0][1] = fmaf(a0, b0.y, acc[0][1]);
      acc[0][2] = fmaf(a0, b0.z, acc[0][2]);
      acc[0][3] = fmaf(a0, b0.w, acc[0][3]);
      acc[0][4] = fmaf(a0, b1.x, acc[0][4]);
      acc[0][5] = fmaf(a0, b1.y, acc[0][5]);
      acc[0][6] = fmaf(a0, b1.z, acc[0][6]);
      acc[0][7] = fmaf(a0, b1.w, acc[0][7]);
      acc[1][0] = fmaf(a1, b0.x, acc[1][0]);
      acc[1][1] = fmaf(a1, b0.y, acc[1][1]);
      acc[1][2] = fmaf(a1, b0.z, acc[1][2]);
      acc[1][3] = fmaf(a1, b0.w, acc[1][3]);
      acc[1][4] = fmaf(a1, b1.x, acc[1][4]);
      acc[1][5] = fmaf(a1, b1.y, acc[1][5]);
      acc[1][6] = fmaf(a1, b1.z, acc[1][6]);
      acc[1][7] = fmaf(a1, b1.w, acc[1][7]);
      acc[2][0] = fmaf(a2, b0.x, acc[2][0]);
      acc[2][1] = fmaf(a2, b0.y, acc[2][1]);
      acc[2][2] = fmaf(a2, b0.z, acc[2][2]);
      acc[2][3] = fmaf(a2, b0.w, acc[2][3]);
      acc[2][4] = fmaf(a2, b1.x, acc[2][4]);
      acc[2][5] = fmaf(a2, b1.y, acc[2][5]);
      acc[2][6] = fmaf(a2, b1.z, acc[2][6]);
      acc[2][7] = fmaf(a2, b1.w, acc[2][7]);
      acc[3][0] = fmaf(a3, b0.x, acc[3][0]);
      acc[3][1] = fmaf(a3, b0.y, acc[3][1]);
      acc[3][2] = fmaf(a3, b0.z, acc[3][2]);
      acc[3][3] = fmaf(a3, b0.w, acc[3][3]);
      acc[3][4] = fmaf(a3, b1.x, acc[3][4]);
      acc[3][5] = fmaf(a3, b1.y, acc[3][5]);
      acc[3][6] = fmaf(a3, b1.z, acc[3][6]);
      acc[3][7] = fmaf(a3, b1.w, acc[3][7]);
    }
    __syncthreads();
  }

  const float4 bias0 = *(const float4*)(B + tx * 8);
  const float4 bias1 = *(const float4*)(B + tx * 8 + 4);
#pragma unroll
  for (int r = 0; r < 4; ++r) {
    const int i = i0 + ty * 4 + r;
    if (i < N_NODES) {
      float4 o0 = make_float4(acc[r][0] + bias0.x, acc[r][1] + bias0.y,
                              acc[r][2] + bias0.z, acc[r][3] + bias0.w);
      float4 o1 = make_float4(acc[r][4] + bias1.x, acc[r][5] + bias1.y,
                              acc[r][6] + bias1.z, acc[r][7] + bias1.w);
      *(float4*)(OUT + (size_t)i * HID + tx * 8) = o0;
      *(float4*)(OUT + (size_t)i * HID + tx * 8 + 4) = o1;
    }
  }
}

// ---------------- overflow fixup (deg > CAP nodes; exact) ----------------
__global__ __launch_bounds__(64) void fixup_k(const int* __restrict__ EI,
                                              const float* __restrict__ X,
                                              const float* __restrict__ W,
                                              const int* __restrict__ cnt,
                                              const int* __restrict__ ovf_cnt,
                                              const int* __restrict__ ovf,
                                              float* __restrict__ OUT) {
  const int n = min(*ovf_cnt, OVF_CAP);
  const int lane = threadIdx.x & 63;
  for (int i = blockIdx.x; i < n; i += gridDim.x) {
    const int e = ovf[i];
    const int dst = EI[e];
    const int src = EI[N_EDGES + e];
    const float inv = 1.0f / (float)(cnt[dst] + 1);
    float s0 = 0.f, s1 = 0.f;
    const int c0 = lane * 2, c1 = lane * 2 + 1;
    for (int k = 0; k < HID; ++k) {
      const float xv = X[(size_t)src * HID + k];
      s0 = fmaf(xv, W[(size_t)c0 * HID + k], s0);
      s1 = fmaf(xv, W[(size_t)c1 * HID + k], s1);
    }
    atomicAdd(OUT + (size_t)dst * HID + c0, s0 * inv);
    atomicAdd(OUT + (size_t)dst * HID + c1, s1 * inv);
  }
}

extern "C" void kernel_launch(void* const* d_in, const int* in_sizes, int n_in,
                              void* d_out, int out_size, void* d_ws, size_t ws_size,
                              hipStream_t stream) {
  const float* X = (const float*)d_in[0];  // [N_NODES, HID]
  const int* EI = (const int*)d_in[1];     // [2, N_EDGES]
  const float* W = (const float*)d_in[2];  // [HID, HID]
  const float* B = (const float*)d_in[3];  // [HID]

  float* OUT = (float*)d_out;  // holds Y after gather, final out after gemm

  // ws layout: buckets[N*CAP] | cnt[N] | ovf_cnt[1] | ovf[OVF_CAP]
  int* buckets = (int*)d_ws;
  int* cnt = buckets + (size_t)N_NODES * CAP;
  int* ovf_cnt = cnt + N_NODES;
  int* ovf = ovf_cnt + 1;

  hipMemsetAsync(cnt, 0, (size_t)(N_NODES + 1) * sizeof(int), stream);

  bucket_k<<<(N_EDGES + 255) / 256, 256, 0, stream>>>(EI, buckets, cnt, ovf_cnt, ovf);
  gatherc_k<<<8 * ((N_NODES + 63) / 64), 256, 0, stream>>>(X, buckets, cnt, OUT);
  gemm_k<<<(N_NODES + 63) / 64, 256, 0, stream>>>(OUT, W, B, OUT);
  fixup_k<<<64, 64, 0, stream>>>(EI, X, W, cnt, ovf_cnt, ovf, OUT);
}

// Round 4
// 154.642 us; speedup vs baseline: 1.8638x; 1.8638x over previous
//
#include <hip/hip_runtime.h>

#define N_NODES 50000
#define N_EDGES 800000
#define HID 128
#define CAP 32        // per-node bucket = 32 ints = exactly 1 cache line
#define OVF_CAP 16384

typedef float f4v __attribute__((ext_vector_type(4)));

// ---------------- bucket edges by dst: buckets[dst][pos] = src ----------------
__global__ __launch_bounds__(256) void bucket_k(const int* __restrict__ EI,
                                                int* __restrict__ buckets,
                                                int* __restrict__ cnt,
                                                int* __restrict__ ovf_cnt,
                                                int* __restrict__ ovf) {
  const int e = blockIdx.x * blockDim.x + threadIdx.x;
  if (e >= N_EDGES) return;
  const int dst = EI[e];            // row 0 = destination
  const int src = EI[N_EDGES + e];  // row 1 = source
  const int pos = atomicAdd(cnt + dst, 1);
  if (pos < CAP) {
    buckets[(size_t)dst * CAP + pos] = src;
  } else {
    const int oi = atomicAdd(ovf_cnt, 1);
    if (oi < OVF_CAP) ovf[oi] = e;
  }
}

// ---------------- Y[d] = (X[d] + sum_src X[src]) / (1+deg[d]) ----------------
// 2 nodes per wave: half = lane>>5 picks the node, lane&31 covers 128 cols as
// float4 (512B contiguous per row -> full cache lines). Inner loop processes
// 8 bucket entries per batch with UNCONDITIONAL loads (padded entries point at
// row 0, L1-hot, masked to x0) -> 16 independent 512B row-segments in flight
// per wave. Bucket = one coalesced 128B line per node, broadcast via shfl.
__global__ __launch_bounds__(256) void gather2_k(const float* __restrict__ X,
                                                 const int* __restrict__ buckets,
                                                 const int* __restrict__ cnt,
                                                 float* __restrict__ Y) {
  const int wid = (int)(((size_t)blockIdx.x * blockDim.x + threadIdx.x) >> 6);
  const int lane = threadIdx.x & 63;
  const int hl = lane & 31;          // lane within half-wave
  const int node = wid * 2 + (lane >> 5);
  const bool valid = node < N_NODES;
  const int deg = valid ? cnt[node] : 0;
  const int m = deg < CAP ? deg : CAP;
  const int c0 = hl * 4;             // this lane's 4 columns

  // lane-parallel bucket read: hl-th src of this half's node (one 128B line)
  int src = 0;
  if (valid && hl < m) src = buckets[(size_t)node * CAP + hl];

  // self row early so it's in flight under the loop
  f4v self = {0.f, 0.f, 0.f, 0.f};
  if (valid) self = *(const f4v*)(X + (size_t)node * HID + c0);

  f4v acc = {0.f, 0.f, 0.f, 0.f};
  const int m8 = (m + 7) & ~7;
  for (int j0 = 0; j0 < m8; j0 += 8) {
    f4v v[8];
    float msk[8];
#pragma unroll
    for (int jj = 0; jj < 8; ++jj) {
      const int j = j0 + jj;
      const int s = __shfl(src, j, 32);   // j>=m -> lane j's src==0 -> row 0 (L1-hot)
      msk[jj] = (j < m) ? 1.f : 0.f;
      v[jj] = *(const f4v*)(X + (size_t)s * HID + c0);
    }
#pragma unroll
    for (int jj = 0; jj < 8; ++jj) acc += v[jj] * msk[jj];
  }

  if (valid) {
    const float inv = 1.0f / (float)(deg + 1);
    const f4v o = (acc + self) * inv;
    *(f4v*)(Y + (size_t)node * HID + c0) = o;
  }
}

// ---------------- out = Y @ W^T + b, IN PLACE over Y (d_out) ----------------
// 64 rows x ALL 128 cols per block -> in-place safe (no cross-block row reuse).
__global__ __launch_bounds__(256) void gemm_k(const float* __restrict__ Y,
                                              const float* __restrict__ W,
                                              const float* __restrict__ B,
                                              float* __restrict__ OUT) {
  __shared__ __align__(16) float As[32][68];
  __shared__ __align__(16) float Bs[32][132];
  const int t = threadIdx.x;
  const int tx = t & 15;  // cols [tx*8, tx*8+8)
  const int ty = t >> 4;  // rows [ty*4, ty*4+4)
  const int i0 = blockIdx.x * 64;
  float acc[4][8];
#pragma unroll
  for (int r = 0; r < 4; ++r)
#pragma unroll
    for (int c = 0; c < 8; ++c) acc[r][c] = 0.f;

  for (int kc = 0; kc < HID; kc += 32) {
#pragma unroll
    for (int it = 0; it < 2; ++it) {
      const int v = t + it * 256;
      const int row = v >> 3;
      const int c4 = v & 7;
      float4 a = make_float4(0.f, 0.f, 0.f, 0.f);
      if (i0 + row < N_NODES)
        a = *(const float4*)(Y + (size_t)(i0 + row) * HID + kc + c4 * 4);
      As[c4 * 4 + 0][row] = a.x;
      As[c4 * 4 + 1][row] = a.y;
      As[c4 * 4 + 2][row] = a.z;
      As[c4 * 4 + 3][row] = a.w;
    }
#pragma unroll
    for (int it = 0; it < 4; ++it) {
      const int v = t + it * 256;
      const int j = v >> 3;
      const int c4 = v & 7;
      const float4 w = *(const float4*)(W + (size_t)j * HID + kc + c4 * 4);
      Bs[c4 * 4 + 0][j] = w.x;
      Bs[c4 * 4 + 1][j] = w.y;
      Bs[c4 * 4 + 2][j] = w.z;
      Bs[c4 * 4 + 3][j] = w.w;
    }
    __syncthreads();
#pragma unroll
    for (int k = 0; k < 32; ++k) {
      const float4 av = *(const float4*)&As[k][ty * 4];
      const float4 b0 = *(const float4*)&Bs[k][tx * 8];
      const float4 b1 = *(const float4*)&Bs[k][tx * 8 + 4];
      const float a0 = av.x, a1 = av.y, a2 = av.z, a3 = av.w;
      acc[0][0] = fmaf(a0, b0.x, acc[0][0]);
      acc[0][1] = fmaf(a0, b0.y, acc[0][1]);
      acc[0][2] = fmaf(a0, b0.z, acc[0][2]);
      acc[0][3] = fmaf(a0, b0.w, acc[0][3]);
      acc[0][4] = fmaf(a0, b1.x, acc[0][4]);
      acc[0][5] = fmaf(a0, b1.y, acc[0][5]);
      acc[0][6] = fmaf(a0, b1.z, acc[0][6]);
      acc[0][7] = fmaf(a0, b1.w, acc[0][7]);
      acc[1][0] = fmaf(a1, b0.x, acc[1][0]);
      acc[1][1] = fmaf(a1, b0.y, acc[1][1]);
      acc[1][2] = fmaf(a1, b0.z, acc[1][2]);
      acc[1][3] = fmaf(a1, b0.w, acc[1][3]);
      acc[1][4] = fmaf(a1, b1.x, acc[1][4]);
      acc[1][5] = fmaf(a1, b1.y, acc[1][5]);
      acc[1][6] = fmaf(a1, b1.z, acc[1][6]);
      acc[1][7] = fmaf(a1, b1.w, acc[1][7]);
      acc[2][0] = fmaf(a2, b0.x, acc[2][0]);
      acc[2][1] = fmaf(a2, b0.y, acc[2][1]);
      acc[2][2] = fmaf(a2, b0.z, acc[2][2]);
      acc[2][3] = fmaf(a2, b0.w, acc[2][3]);
      acc[2][4] = fmaf(a2, b1.x, acc[2][4]);
      acc[2][5] = fmaf(a2, b1.y, acc[2][5]);
      acc[2][6] = fmaf(a2, b1.z, acc[2][6]);
      acc[2][7] = fmaf(a2, b1.w, acc[2][7]);
      acc[3][0] = fmaf(a3, b0.x, acc[3][0]);
      acc[3][1] = fmaf(a3, b0.y, acc[3][1]);
      acc[3][2] = fmaf(a3, b0.z, acc[3][2]);
      acc[3][3] = fmaf(a3, b0.w, acc[3][3]);
      acc[3][4] = fmaf(a3, b1.x, acc[3][4]);
      acc[3][5] = fmaf(a3, b1.y, acc[3][5]);
      acc[3][6] = fmaf(a3, b1.z, acc[3][6]);
      acc[3][7] = fmaf(a3, b1.w, acc[3][7]);
    }
    __syncthreads();
  }

  const float4 bias0 = *(const float4*)(B + tx * 8);
  const float4 bias1 = *(const float4*)(B + tx * 8 + 4);
#pragma unroll
  for (int r = 0; r < 4; ++r) {
    const int i = i0 + ty * 4 + r;
    if (i < N_NODES) {
      float4 o0 = make_float4(acc[r][0] + bias0.x, acc[r][1] + bias0.y,
                              acc[r][2] + bias0.z, acc[r][3] + bias0.w);
      float4 o1 = make_float4(acc[r][4] + bias1.x, acc[r][5] + bias1.y,
                              acc[r][6] + bias1.z, acc[r][7] + bias1.w);
      *(float4*)(OUT + (size_t)i * HID + tx * 8) = o0;
      *(float4*)(OUT + (size_t)i * HID + tx * 8 + 4) = o1;
    }
  }
}

// ---------------- overflow fixup (deg > CAP nodes; exact) ----------------
__global__ __launch_bounds__(64) void fixup_k(const int* __restrict__ EI,
                                              const float* __restrict__ X,
                                              const float* __restrict__ W,
                                              const int* __restrict__ cnt,
                                              const int* __restrict__ ovf_cnt,
                                              const int* __restrict__ ovf,
                                              float* __restrict__ OUT) {
  const int n = min(*ovf_cnt, OVF_CAP);
  const int lane = threadIdx.x & 63;
  for (int i = blockIdx.x; i < n; i += gridDim.x) {
    const int e = ovf[i];
    const int dst = EI[e];
    const int src = EI[N_EDGES + e];
    const float inv = 1.0f / (float)(cnt[dst] + 1);
    float s0 = 0.f, s1 = 0.f;
    const int c0 = lane * 2, c1 = lane * 2 + 1;
    for (int k = 0; k < HID; ++k) {
      const float xv = X[(size_t)src * HID + k];
      s0 = fmaf(xv, W[(size_t)c0 * HID + k], s0);
      s1 = fmaf(xv, W[(size_t)c1 * HID + k], s1);
    }
    atomicAdd(OUT + (size_t)dst * HID + c0, s0 * inv);
    atomicAdd(OUT + (size_t)dst * HID + c1, s1 * inv);
  }
}

extern "C" void kernel_launch(void* const* d_in, const int* in_sizes, int n_in,
                              void* d_out, int out_size, void* d_ws, size_t ws_size,
                              hipStream_t stream) {
  const float* X = (const float*)d_in[0];  // [N_NODES, HID]
  const int* EI = (const int*)d_in[1];     // [2, N_EDGES]
  const float* W = (const float*)d_in[2];  // [HID, HID]
  const float* B = (const float*)d_in[3];  // [HID]

  float* OUT = (float*)d_out;  // holds Y after gather, final out after gemm

  // ws layout: buckets[N*CAP] | cnt[N] | ovf_cnt[1] | ovf[OVF_CAP]
  int* buckets = (int*)d_ws;
  int* cnt = buckets + (size_t)N_NODES * CAP;
  int* ovf_cnt = cnt + N_NODES;
  int* ovf = ovf_cnt + 1;

  hipMemsetAsync(cnt, 0, (size_t)(N_NODES + 1) * sizeof(int), stream);

  bucket_k<<<(N_EDGES + 255) / 256, 256, 0, stream>>>(EI, buckets, cnt, ovf_cnt, ovf);
  // 2 nodes per wave -> 25000 waves -> with 4 waves/block: 6250 blocks
  gather2_k<<<(N_NODES / 2 * 64 + 255) / 256 + 1, 256, 0, stream>>>(X, buckets, cnt, OUT);
  gemm_k<<<(N_NODES + 63) / 64, 256, 0, stream>>>(OUT, W, B, OUT);
  fixup_k<<<64, 64, 0, stream>>>(EI, X, W, cnt, ovf_cnt, ovf, OUT);
}

// Round 5
// 122.786 us; speedup vs baseline: 2.3473x; 1.2594x over previous
//
#include <hip/hip_runtime.h>

#define N_NODES 50000
#define N_EDGES 800000
#define HID 128
#define CAP 32        // per-node bucket = 32 ints = exactly 1 cache line
#define OVF_CAP 16384

typedef float f4v __attribute__((ext_vector_type(4)));
typedef short s8v __attribute__((ext_vector_type(8)));
typedef unsigned short u16;

__device__ __forceinline__ u16 f2bf(float f) {  // RNE fp32 -> bf16
  union { float f; unsigned u; } v;
  v.f = f;
  const unsigned r = v.u + 0x7FFFu + ((v.u >> 16) & 1u);
  return (u16)(r >> 16);
}
__device__ __forceinline__ float bf2f(u16 h) {
  union { unsigned u; float f; } v;
  v.u = ((unsigned)h) << 16;
  return v.f;
}

// ---------------- W fp32 -> bf16 (16384 elems) ----------------
__global__ __launch_bounds__(256) void cvtw_k(const float* __restrict__ W,
                                              u16* __restrict__ Wb) {
  const int i = blockIdx.x * 256 + threadIdx.x;
  if (i < HID * HID) Wb[i] = f2bf(W[i]);
}

// ---------------- bucket edges by dst: buckets[dst][pos] = src ----------------
__global__ __launch_bounds__(256) void bucket_k(const int* __restrict__ EI,
                                                int* __restrict__ buckets,
                                                int* __restrict__ cnt,
                                                int* __restrict__ ovf_cnt,
                                                int* __restrict__ ovf) {
  const int e = blockIdx.x * blockDim.x + threadIdx.x;
  if (e >= N_EDGES) return;
  const int dst = EI[e];            // row 0 = destination
  const int src = EI[N_EDGES + e];  // row 1 = source
  const int pos = atomicAdd(cnt + dst, 1);
  if (pos < CAP) {
    buckets[(size_t)dst * CAP + pos] = src;
  } else {
    const int oi = atomicAdd(ovf_cnt, 1);
    if (oi < OVF_CAP) ovf[oi] = e;
  }
}

// ---------------- Hb = bf16(X @ W^T + bias), MFMA 16x16x32 bf16 ----------------
// 4 waves/block, each wave owns 16 rows x all 128 cols (8 j-tiles x 4 k-chunks).
// A-frag: lane holds X[i0+(l&15)][kc*32+(l>>4)*8 ..+7] (fp32->bf16 in regs).
// B-frag: B[k][j]=W[j][k] -> lane holds Wb[jt*16+(l&15)][kc*32+(l>>4)*8 ..+7].
// C/D: col=lane&15, row=(lane>>4)*4+reg (m89-verified).
__global__ __launch_bounds__(256) void gemmh_k(const float* __restrict__ X,
                                               const u16* __restrict__ Wb,
                                               const float* __restrict__ Bias,
                                               u16* __restrict__ Hb) {
  const int lane = threadIdx.x & 63;
  const int wv = threadIdx.x >> 6;
  const int i0 = blockIdx.x * 64 + wv * 16;
  const int r16 = lane & 15;
  const int kb = lane >> 4;

  int arow = i0 + r16;
  if (arow >= N_NODES) arow = N_NODES - 1;  // clamp reads; stores guarded

  s8v a[4];
#pragma unroll
  for (int kc = 0; kc < 4; ++kc) {
    const int k0 = kc * 32 + kb * 8;
    const float4 x0 = *(const float4*)(X + (size_t)arow * HID + k0);
    const float4 x1 = *(const float4*)(X + (size_t)arow * HID + k0 + 4);
    s8v t;
    t[0] = (short)f2bf(x0.x); t[1] = (short)f2bf(x0.y);
    t[2] = (short)f2bf(x0.z); t[3] = (short)f2bf(x0.w);
    t[4] = (short)f2bf(x1.x); t[5] = (short)f2bf(x1.y);
    t[6] = (short)f2bf(x1.z); t[7] = (short)f2bf(x1.w);
    a[kc] = t;
  }

  f4v acc[8];
#pragma unroll
  for (int jt = 0; jt < 8; ++jt) acc[jt] = (f4v){0.f, 0.f, 0.f, 0.f};

#pragma unroll
  for (int jt = 0; jt < 8; ++jt) {
    const int j = jt * 16 + r16;
#pragma unroll
    for (int kc = 0; kc < 4; ++kc) {
      const int k0 = kc * 32 + kb * 8;
      const s8v b = *(const s8v*)(Wb + (size_t)j * HID + k0);
      acc[jt] = __builtin_amdgcn_mfma_f32_16x16x32_bf16(a[kc], b, acc[jt], 0, 0, 0);
    }
  }

#pragma unroll
  for (int jt = 0; jt < 8; ++jt) {
    const int j = jt * 16 + r16;
    const float bias = Bias[j];
#pragma unroll
    for (int r = 0; r < 4; ++r) {
      const int row = i0 + kb * 4 + r;
      if (row < N_NODES) Hb[(size_t)row * HID + j] = f2bf(acc[jt][r] + bias);
    }
  }
}

// ---------------- OUT[d] = (Hb[d] + sum_src Hb[src]) / (1+deg[d]) ----------------
// 4 nodes/wave: 16 lanes/node, lane = 16B (8 bf16) -> one load instruction =
// 4 full 256B row-segments; 8-deep unconditional masked batches -> 32 segments
// in flight per wave. fp32 accumulate, fp32 output.
__global__ __launch_bounds__(256) void gatherh_k(const u16* __restrict__ Hb,
                                                 const int* __restrict__ buckets,
                                                 const int* __restrict__ cnt,
                                                 float* __restrict__ OUT) {
  const int wid = (int)(((size_t)blockIdx.x * blockDim.x + threadIdx.x) >> 6);
  const int lane = threadIdx.x & 63;
  const int q = lane >> 4;   // node slot within wave
  const int hl = lane & 15;  // lane within 16-lane group
  const int node = wid * 4 + q;
  const bool valid = node < N_NODES;
  const int nd = valid ? node : 0;
  const int deg = cnt[nd];
  const int m = deg < CAP ? deg : CAP;
  const int c0 = hl * 8;  // bf16 column offset (16B per lane)

  // coalesced bucket read: 32 ints per node via two 16-lane reads
  int src0 = 0, src1 = 0;
  if (hl < m) src0 = buckets[(size_t)nd * CAP + hl];
  if (hl + 16 < m) src1 = buckets[(size_t)nd * CAP + 16 + hl];

  const s8v selfv = *(const s8v*)(Hb + (size_t)nd * HID + c0);

  f4v acc0 = {0.f, 0.f, 0.f, 0.f};
  f4v acc1 = {0.f, 0.f, 0.f, 0.f};

  for (int j0 = 0; j0 < CAP; j0 += 8) {
    if (!__any(j0 < m)) break;
    const int sv = (j0 >= 16) ? src1 : src0;
    const int jb = j0 & 15;
    s8v v[8];
    float msk[8];
#pragma unroll
    for (int jj = 0; jj < 8; ++jj) {
      const int s = __shfl(sv, jb + jj, 16);  // padded -> lane's src==0 -> row 0 (hot)
      msk[jj] = (j0 + jj < m) ? 1.f : 0.f;
      v[jj] = *(const s8v*)(Hb + (size_t)s * HID + c0);
    }
#pragma unroll
    for (int jj = 0; jj < 8; ++jj) {
#pragma unroll
      for (int t = 0; t < 4; ++t) {
        acc0[t] += bf2f((u16)v[jj][t]) * msk[jj];
        acc1[t] += bf2f((u16)v[jj][t + 4]) * msk[jj];
      }
    }
  }

  if (valid) {
    const float inv = 1.0f / (float)(deg + 1);
    f4v o0, o1;
#pragma unroll
    for (int t = 0; t < 4; ++t) {
      o0[t] = (acc0[t] + bf2f((u16)selfv[t])) * inv;
      o1[t] = (acc1[t] + bf2f((u16)selfv[t + 4])) * inv;
    }
    *(f4v*)(OUT + (size_t)node * HID + c0) = o0;
    *(f4v*)(OUT + (size_t)node * HID + c0 + 4) = o1;
  }
}

// ---------------- overflow fixup: OUT[dst] += Hb[src]/(1+deg[dst]) ----------------
__global__ __launch_bounds__(64) void fixup_k(const int* __restrict__ EI,
                                              const u16* __restrict__ Hb,
                                              const int* __restrict__ cnt,
                                              const int* __restrict__ ovf_cnt,
                                              const int* __restrict__ ovf,
                                              float* __restrict__ OUT) {
  const int n = min(*ovf_cnt, OVF_CAP);
  const int lane = threadIdx.x & 63;
  for (int i = blockIdx.x; i < n; i += gridDim.x) {
    const int e = ovf[i];
    const int dst = EI[e];
    const int src = EI[N_EDGES + e];
    const float inv = 1.0f / (float)(cnt[dst] + 1);
    const float h0 = bf2f(Hb[(size_t)src * HID + lane * 2]);
    const float h1 = bf2f(Hb[(size_t)src * HID + lane * 2 + 1]);
    atomicAdd(OUT + (size_t)dst * HID + lane * 2, h0 * inv);
    atomicAdd(OUT + (size_t)dst * HID + lane * 2 + 1, h1 * inv);
  }
}

extern "C" void kernel_launch(void* const* d_in, const int* in_sizes, int n_in,
                              void* d_out, int out_size, void* d_ws, size_t ws_size,
                              hipStream_t stream) {
  const float* X = (const float*)d_in[0];   // [N_NODES, HID]
  const int* EI = (const int*)d_in[1];      // [2, N_EDGES]
  const float* W = (const float*)d_in[2];   // [HID, HID]
  const float* Bias = (const float*)d_in[3];// [HID]

  float* OUT = (float*)d_out;

  // ws layout (bytes):
  //   Hb      @ 0          : 50000*128*2 = 12,800,000
  //   buckets @ 12,800,000 : 50000*32*4  =  6,400,000
  //   Wb      @ 19,200,000 : 16384*2     =     32,768
  //   cnt     @ 19,232,768 : 50000*4     =    200,000
  //   ovf_cnt @ 19,432,768 : 4
  //   ovf     @ 19,432,772 : OVF_CAP*4
  char* ws = (char*)d_ws;
  u16* Hb = (u16*)(ws);
  int* buckets = (int*)(ws + 12800000);
  u16* Wb = (u16*)(ws + 19200000);
  int* cnt = (int*)(ws + 19232768);
  int* ovf_cnt = (int*)(ws + 19432768);
  int* ovf = (int*)(ws + 19432772);

  hipMemsetAsync(cnt, 0, (size_t)N_NODES * sizeof(int) + sizeof(int), stream);

  cvtw_k<<<(HID * HID + 255) / 256, 256, 0, stream>>>(W, Wb);
  bucket_k<<<(N_EDGES + 255) / 256, 256, 0, stream>>>(EI, buckets, cnt, ovf_cnt, ovf);
  gemmh_k<<<(N_NODES + 63) / 64, 256, 0, stream>>>(X, Wb, Bias, Hb);
  gatherh_k<<<(N_NODES + 15) / 16, 256, 0, stream>>>(Hb, buckets, cnt, OUT);
  fixup_k<<<64, 64, 0, stream>>>(EI, Hb, cnt, ovf_cnt, ovf, OUT);
}